// Round 7
// baseline (2231.724 us; speedup 1.0000x reference)
//
#include <hip/hip_runtime.h>
#include <math.h>

// SLIC superpixel segmentation — bit-faithful f32 reimplementation of the JAX ref
// (XLA CPU semantics). Numerics decisions, all aimed at exact label match:
//  - dot(feats, centers) replicates Eigen sgemm: sequential k=0..4 FMA chain.
//  - f_sq / c_sq: rounded squares, sequential adds, NO fma (fp contract off).
//  - d = (f_sq + c_sq) - 2*dot, three separately-rounded ops.
//  - strict-< argmin (first occurrence, == jnp.argmin).
//  - segment_sum: EXACT ascending-pixel-index sequential adds per cluster.
// R7: dispatch-count attack (R6 showed total is pinned at ~12us/dispatch x42,
// busy deltas invisible). Counting sort (prefix+scatter+update, 3 dispatches/
// iter) replaced by ONE label-scan kernel: 1 wave per (batch,cluster) scans
// uchar labels coalesced, ballot-selects its pixels, replays them in ascending
// pixel order via ctz+shfl into 5 serial accumulators — add order is globally
// ascending, bit-identical to the sort path. k_init folded into first assign.
// 42 -> 21 dispatches. R5 lesson: NO cg::grid.sync (80us/sync).

#pragma clang fp contract(off)

#define BATCH 8
#define HH 224
#define WW 224
#define HWPIX (HH * WW)        // 50176 = 784*64, exact
#define KSEG 100
#define NTILE 49               // 1024-px assign tiles per batch
#define NITER 10

__device__ __forceinline__ float get_ratio() {
    double S = sqrt((double)(HH * WW) / (double)KSEG);
    return (float)(10.0 / S);
}

// 4 pixels per thread (n0 + {0,256,512,768}).
// initc: compute grid-init centers in-LDS (no global centers read).
// writeout: final pass — write outLab/outMean instead of labels.
__global__ void k_assign(const float* __restrict__ img, const float* __restrict__ centers,
                         unsigned char* __restrict__ labels, float* __restrict__ outLab,
                         float* __restrict__ outMean, int initc, int writeout) {
#pragma clang fp contract(off)
    __shared__ float c8[KSEG * 8];   // [c0,c1,c2,c3,c4,csq,pad,pad] per cluster
    int b = blockIdx.y, tile = blockIdx.x, tid = threadIdx.x;
    float ratio = get_ratio();

    if (initc) {
        if (tid < KSEG) {
            int i = tid / 10, j = tid % 10;
            int y = (int)floor(((i + 0.5) * (double)HH) / 10.0);
            int x = (int)floor(((j + 0.5) * (double)WW) / 10.0);
            int n = y * WW + x;
            const float* p = img + ((size_t)b * HWPIX + n) * 3;
            c8[tid * 8 + 0] = (float)y * ratio;
            c8[tid * 8 + 1] = (float)x * ratio;
            c8[tid * 8 + 2] = p[0];
            c8[tid * 8 + 3] = p[1];
            c8[tid * 8 + 4] = p[2];
        }
    } else {
        for (int i = tid; i < KSEG * 5; i += 256) {
            int k = i / 5, f = i - 5 * k;
            c8[k * 8 + f] = centers[(size_t)b * KSEG * 5 + i];
        }
    }
    __syncthreads();
    if (tid < KSEG) {
        const float* ck = c8 + tid * 8;
        float s = ck[0] * ck[0];             // XLA fused mul+reduce: no fma, seq adds
        s = s + ck[1] * ck[1];
        s = s + ck[2] * ck[2];
        s = s + ck[3] * ck[3];
        s = s + ck[4] * ck[4];
        c8[tid * 8 + 5] = s;
    }
    __syncthreads();

    int n0 = tile * 1024 + tid;
    float yf[4], xf[4], rr[4], gg[4], bb[4], fsq[4], dmin[4];
    int kb[4];
#pragma unroll
    for (int p = 0; p < 4; ++p) {
        int n = n0 + p * 256;
        int y = n / WW, x = n - y * WW;
        yf[p] = (float)y * ratio;
        xf[p] = (float)x * ratio;
        const float* pp = img + ((size_t)b * HWPIX + n) * 3;
        rr[p] = pp[0]; gg[p] = pp[1]; bb[p] = pp[2];
        float s = yf[p] * yf[p];             // no fma, seq adds (XLA reduce)
        s = s + xf[p] * xf[p];
        s = s + rr[p] * rr[p];
        s = s + gg[p] * gg[p];
        s = s + bb[p] * bb[p];
        fsq[p] = s;
        dmin[p] = INFINITY;
        kb[p] = 0;
    }

    for (int k = 0; k < KSEG; ++k) {
        float4 v0 = *reinterpret_cast<const float4*>(&c8[k * 8]);  // ds_read_b128
        float c4v = c8[k * 8 + 4];
        float csqv = c8[k * 8 + 5];
#pragma unroll
        for (int p = 0; p < 4; ++p) {
            // Eigen sgemm micro-kernel: sequential FMA chain over contracted dim
            float dot = yf[p] * v0.x;        // == fma(yf, c0, 0)
            dot = __fmaf_rn(xf[p], v0.y, dot);
            dot = __fmaf_rn(rr[p], v0.z, dot);
            dot = __fmaf_rn(gg[p], v0.w, dot);
            dot = __fmaf_rn(bb[p], c4v, dot);
            float d = (fsq[p] + csqv) - 2.0f * dot;   // three separately-rounded ops
            if (d < dmin[p]) { dmin[p] = d; kb[p] = k; }  // strict < == jnp.argmin
        }
    }

    if (!writeout) {
#pragma unroll
        for (int p = 0; p < 4; ++p)
            labels[(size_t)b * HWPIX + n0 + p * 256] = (unsigned char)kb[p];
    } else {
#pragma unroll
        for (int p = 0; p < 4; ++p) {
            int n = n0 + p * 256;
            outLab[(size_t)b * HWPIX + n] = (float)kb[p];
            float* om = outMean + ((size_t)b * HWPIX + n) * 3;
            om[0] = c8[kb[p] * 8 + 2];
            om[1] = c8[kb[p] * 8 + 3];
            om[2] = c8[kb[p] * 8 + 4];
        }
    }
}

// One wave per (batch,cluster): scan labels (coalesced uchar), ballot-select,
// replay matched pixels in ascending pixel order via ctz+shfl. Lanes 0..4 keep
// the 5 channel accumulators; add order == reference segment_sum order.
__global__ void k_update(const float* __restrict__ img, const unsigned char* __restrict__ labels,
                         float* __restrict__ centers, int initc) {
#pragma clang fp contract(off)
    int k = blockIdx.x, b = blockIdx.y;
    int lane = threadIdx.x;                  // 64 threads = 1 wave
    const unsigned char* lb = labels + (size_t)b * HWPIX;
    const float* ib = img + (size_t)b * HWPIX * 3;
    float ratio = get_ratio();
    float s = 0.f;
    int cnt = 0;
    for (int c0 = 0; c0 < HWPIX; c0 += 64) {
        int n = c0 + lane;
        bool m = (lb[n] == k);
        unsigned long long mask = __ballot(m);
        if (mask == 0ull) continue;
        float f0 = 0.f, f1 = 0.f, f2 = 0.f, f3 = 0.f, f4 = 0.f;
        if (m) {
            int y = n / WW, x = n - y * WW;
            f0 = (float)y * ratio;
            f1 = (float)x * ratio;
            const float* p = ib + (size_t)n * 3;
            f2 = p[0]; f3 = p[1]; f4 = p[2];
        }
        cnt += __popcll(mask);
        while (mask) {
            int src = __builtin_ctzll(mask); // ascending lane == ascending pixel
            mask &= mask - 1;
            float v0 = __shfl(f0, src);
            float v1 = __shfl(f1, src);
            float v2 = __shfl(f2, src);
            float v3 = __shfl(f3, src);
            float v4 = __shfl(f4, src);
            float v = (lane == 0) ? v0 : (lane == 1) ? v1 : (lane == 2) ? v2
                      : (lane == 3) ? v3 : v4;
            if (lane < 5) s = s + v;         // exact ascending serial chain
        }
    }
    if (lane < 5) {
        if (cnt > 0) {                       // where(counts>0, sums/counts, old)
            centers[(b * KSEG + k) * 5 + lane] = s / (float)cnt;
        } else if (initc) {
            // materialize the grid-init value (global centers was never written)
            int i = k / 10, j = k % 10;
            int y = (int)floor(((i + 0.5) * (double)HH) / 10.0);
            int x = (int)floor(((j + 0.5) * (double)WW) / 10.0);
            int n = y * WW + x;
            const float* p = ib + (size_t)n * 3;
            float val = (lane == 0) ? (float)y * ratio
                      : (lane == 1) ? (float)x * ratio
                      : p[lane - 2];
            centers[(b * KSEG + k) * 5 + lane] = val;
        }
    }
}

extern "C" void kernel_launch(void* const* d_in, const int* in_sizes, int n_in,
                              void* d_out, int out_size, void* d_ws, size_t ws_size,
                              hipStream_t stream) {
    const float* img = (const float*)d_in[0];
    float* outLab = (float*)d_out;                         // [8,224,224] labels as f32
    float* outMean = outLab + (size_t)BATCH * HWPIX;       // [8,224,224,3]

    char* ws = (char*)d_ws;
    float* centers         = (float*)ws;          ws += (size_t)BATCH * KSEG * 5 * sizeof(float);
    unsigned char* labels  = (unsigned char*)ws;  ws += (size_t)BATCH * HWPIX;

    for (int it = 0; it < NITER; ++it) {
        k_assign<<<dim3(NTILE, BATCH), 256, 0, stream>>>(img, centers, labels,
                                                         outLab, outMean,
                                                         it == 0 ? 1 : 0, 0);
        k_update<<<dim3(KSEG, BATCH), 64, 0, stream>>>(img, labels, centers,
                                                       it == 0 ? 1 : 0);
    }
    k_assign<<<dim3(NTILE, BATCH), 256, 0, stream>>>(img, centers, labels,
                                                     outLab, outMean, 0, 1);
}

// Round 8
// 927.598 us; speedup vs baseline: 2.4059x; 2.4059x over previous
//
#include <hip/hip_runtime.h>
#include <math.h>

// SLIC superpixel segmentation — bit-faithful f32 reimplementation of the JAX ref
// (XLA CPU semantics). Numerics decisions, all aimed at exact label match:
//  - dot(feats, centers) replicates Eigen sgemm: sequential k=0..4 FMA chain.
//  - f_sq / c_sq: rounded squares, sequential adds, NO fma (fp contract off).
//  - d = (f_sq + c_sq) - 2*dot, three separately-rounded ops.
//  - strict-< argmin (first occurrence, == jnp.argmin).
//  - segment_sum: EXACT ascending-pixel-index sequential adds per cluster,
//    via stable counting sort (sub-tile hist -> prefix -> rank scatter).
// R8: R7 calibration showed dispatch overhead is ~1.2us (not 12) -> R6's 747us
// is ~700us BUSY, and the hidden hog is k_prefix (~40us x10: 8 blocks, 100
// threads, 400B-stride uncoalesced loads, two serial passes). Replaced by:
//  - blockHist stored TRANSPOSED [b][k][blk] (cluster rows contiguous);
//  - k_mid: one wave per (batch,cluster): cbase = lane-parallel sum of the
//    contiguous j<k region + shfl-scan row prefix -> offsets/ccount. All
//    integer, exact; float math untouched -> outputs bit-identical to R6.
// R7's ballot/ctz label-scan update is REVERTED (latency-serialized, 214us).

#pragma clang fp contract(off)

#define BATCH 8
#define HH 224
#define WW 224
#define HWPIX (HH * WW)        // 50176
#define KSEG 100
#define NSUB 196               // 256-px sub-tiles per batch
#define NTILE 49               // 1024-px assign tiles per batch
#define NITER 10
#define UCHUNK 2048            // update LDS chunk: 5*(2048+1)*4B = 40.98KB

__device__ __forceinline__ float get_ratio() {
    double S = sqrt((double)(HH * WW) / (double)KSEG);
    return (float)(10.0 / S);
}

__global__ void k_init(const float* __restrict__ img, float* __restrict__ centers) {
#pragma clang fp contract(off)
    int b = blockIdx.x;
    int k = threadIdx.x;
    if (k >= KSEG) return;
    int i = k / 10, j = k % 10;
    int y = (int)floor(((i + 0.5) * (double)HH) / 10.0);
    int x = (int)floor(((j + 0.5) * (double)WW) / 10.0);
    float ratio = get_ratio();
    int n = y * WW + x;
    const float* p = img + ((size_t)b * HWPIX + n) * 3;
    float* c = centers + (b * KSEG + k) * 5;
    c[0] = (float)y * ratio;
    c[1] = (float)x * ratio;
    c[2] = p[0];
    c[3] = p[1];
    c[4] = p[2];
}

// 4 pixels per thread (n0 + {0,256,512,768}); hist per 256-px sub-tile,
// stored TRANSPOSED: blockHist[(b*KSEG + k)*NSUB + sub].
// mode 0: labels + histogram.  mode 1: final outputs.
__global__ void k_assign(const float* __restrict__ img, const float* __restrict__ centers,
                         int* __restrict__ labels, int* __restrict__ blockHist,
                         float* __restrict__ outLab, float* __restrict__ outMean, int mode) {
#pragma clang fp contract(off)
    __shared__ float c8[KSEG * 8];   // [c0,c1,c2,c3,c4,csq,pad,pad] per cluster
    __shared__ int hist[4 * KSEG];
    int b = blockIdx.y, tile = blockIdx.x, tid = threadIdx.x;

    for (int i = tid; i < KSEG * 5; i += 256) {
        int k = i / 5, f = i - 5 * k;
        c8[k * 8 + f] = centers[(size_t)b * KSEG * 5 + i];
    }
    for (int i = tid; i < 4 * KSEG; i += 256) hist[i] = 0;
    __syncthreads();
    if (tid < KSEG) {
        const float* ck = c8 + tid * 8;
        float s = ck[0] * ck[0];             // XLA fused mul+reduce: no fma, seq adds
        s = s + ck[1] * ck[1];
        s = s + ck[2] * ck[2];
        s = s + ck[3] * ck[3];
        s = s + ck[4] * ck[4];
        c8[tid * 8 + 5] = s;
    }
    __syncthreads();

    float ratio = get_ratio();
    int n0 = tile * 1024 + tid;
    float yf[4], xf[4], rr[4], gg[4], bb[4], fsq[4], dmin[4];
    int kb[4];
#pragma unroll
    for (int p = 0; p < 4; ++p) {
        int n = n0 + p * 256;
        int y = n / WW, x = n - y * WW;
        yf[p] = (float)y * ratio;
        xf[p] = (float)x * ratio;
        const float* pp = img + ((size_t)b * HWPIX + n) * 3;
        rr[p] = pp[0]; gg[p] = pp[1]; bb[p] = pp[2];
        float s = yf[p] * yf[p];             // no fma, seq adds (XLA reduce)
        s = s + xf[p] * xf[p];
        s = s + rr[p] * rr[p];
        s = s + gg[p] * gg[p];
        s = s + bb[p] * bb[p];
        fsq[p] = s;
        dmin[p] = INFINITY;
        kb[p] = 0;
    }

    for (int k = 0; k < KSEG; ++k) {
        float4 v0 = *reinterpret_cast<const float4*>(&c8[k * 8]);  // ds_read_b128
        float c4v = c8[k * 8 + 4];
        float csqv = c8[k * 8 + 5];
#pragma unroll
        for (int p = 0; p < 4; ++p) {
            // Eigen sgemm micro-kernel: sequential FMA chain over contracted dim
            float dot = yf[p] * v0.x;        // == fma(yf, c0, 0)
            dot = __fmaf_rn(xf[p], v0.y, dot);
            dot = __fmaf_rn(rr[p], v0.z, dot);
            dot = __fmaf_rn(gg[p], v0.w, dot);
            dot = __fmaf_rn(bb[p], c4v, dot);
            float d = (fsq[p] + csqv) - 2.0f * dot;   // three separately-rounded ops
            if (d < dmin[p]) { dmin[p] = d; kb[p] = k; }  // strict < == jnp.argmin
        }
    }

#pragma unroll
    for (int p = 0; p < 4; ++p)
        labels[(size_t)b * HWPIX + n0 + p * 256] = kb[p];

    if (mode == 0) {
#pragma unroll
        for (int p = 0; p < 4; ++p) atomicAdd(&hist[p * KSEG + kb[p]], 1);
        __syncthreads();
        for (int i = tid; i < 4 * KSEG; i += 256) {
            int part = i / KSEG, k = i - part * KSEG;
            blockHist[((size_t)b * KSEG + k) * NSUB + tile * 4 + part] = hist[i];
        }
    } else {
#pragma unroll
        for (int p = 0; p < 4; ++p) {
            int n = n0 + p * 256;
            outLab[(size_t)b * HWPIX + n] = (float)kb[p];
            float* om = outMean + ((size_t)b * HWPIX + n) * 3;
            om[0] = c8[kb[p] * 8 + 2];
            om[1] = c8[kb[p] * 8 + 3];
            om[2] = c8[kb[p] * 8 + 4];
        }
    }
}

// One wave per (batch,cluster). cbase = sum of contiguous rows j<k (coalesced);
// row exclusive prefix via shfl scan -> offsets; ccount = row total. Integer.
__global__ void k_mid(const int* __restrict__ blockHist, int* __restrict__ offsets,
                      int* __restrict__ cbase, int* __restrict__ ccount) {
    int k = blockIdx.x, b = blockIdx.y;
    int lane = threadIdx.x;                  // 64 threads = 1 wave
    const int* histB = blockHist + (size_t)b * KSEG * NSUB;

    // cbase: sum of blockHist[b][0 .. k*NSUB) — contiguous, lane-coalesced
    int partial = 0;
    int len = k * NSUB;
    for (int i = lane; i < len; i += 64) partial += histB[i];
    for (int d = 32; d > 0; d >>= 1) partial += __shfl_down(partial, d);
    int base = __shfl(partial, 0);           // broadcast

    // exclusive prefix over this cluster's row (196 entries), 64 at a time
    const int* row = histB + (size_t)k * NSUB;
    int* orow = offsets + ((size_t)b * KSEG + k) * NSUB;
    int carry = 0;
    for (int c0 = 0; c0 < NSUB; c0 += 64) {
        int i = c0 + lane;
        int v0 = (i < NSUB) ? row[i] : 0;
        int v = v0;
        for (int d = 1; d < 64; d <<= 1) {   // Hillis-Steele inclusive scan
            int t = __shfl_up(v, d);
            if (lane >= d) v += t;
        }
        if (i < NSUB) orow[i] = base + carry + (v - v0);  // exclusive
        carry += __shfl(v, 63);              // chunk total
    }
    if (lane == 0) {
        cbase[b * KSEG + k] = base;
        ccount[b * KSEG + k] = carry;
    }
}

// Stable scatter with wave-shuffle rank; offsets read from transposed layout.
__global__ void k_scatter(const float* __restrict__ img, const int* __restrict__ labels,
                          const int* __restrict__ offsets, float* __restrict__ sortedF) {
#pragma clang fp contract(off)
    __shared__ int whist[4 * KSEG];
    int b = blockIdx.y, sub = blockIdx.x, tid = threadIdx.x;
    int lane = tid & 63, w = tid >> 6;
    int n = sub * 256 + tid;
    int my = labels[(size_t)b * HWPIX + n];

    for (int i = tid; i < 4 * KSEG; i += 256) whist[i] = 0;
    __syncthreads();

    int rank_w = 0, cnt_w = 0;
    for (int l = 0; l < 64; ++l) {
        int ll = __shfl(my, l);
        if (ll == my) { cnt_w++; if (l < lane) rank_w++; }
    }
    if (rank_w == 0) whist[w * KSEG + my] = cnt_w;   // one writer per (wave,label)
    __syncthreads();
    int rank = rank_w;
    for (int w2 = 0; w2 < w; ++w2) rank += whist[w2 * KSEG + my];

    int pos = offsets[((size_t)b * KSEG + my) * NSUB + sub] + rank;
    int y = n / WW, x = n - y * WW;
    float ratio = get_ratio();
    const float* p = img + ((size_t)b * HWPIX + n) * 3;   // coalesced
    float* sf = sortedF + (size_t)b * 5 * HWPIX;
    sf[0 * HWPIX + pos] = (float)y * ratio;
    sf[1 * HWPIX + pos] = (float)x * ratio;
    sf[2 * HWPIX + pos] = p[0];
    sf[3 * HWPIX + pos] = p[1];
    sf[4 * HWPIX + pos] = p[2];
}

// One workgroup per (batch,cluster): 256 threads stage 5 x cnt sorted values
// into LDS (lane-coalesced), then 5 lanes do the EXACT ascending serial sums.
__global__ void k_update(const float* __restrict__ sortedF, const int* __restrict__ cbase,
                         const int* __restrict__ ccount, float* __restrict__ centers) {
#pragma clang fp contract(off)
    __shared__ float buf[5][UCHUNK + 1];     // +1: rows land in different banks
    int k = blockIdx.x, b = blockIdx.y, tid = threadIdx.x;
    int base = cbase[b * KSEG + k], cnt = ccount[b * KSEG + k];
    const float* sf0 = sortedF + (size_t)b * 5 * HWPIX + base;
    float acc = 0.f;
    for (int c0 = 0; c0 < cnt; c0 += UCHUNK) {
        int m = min(UCHUNK, cnt - c0);
        for (int ch = 0; ch < 5; ++ch) {
            const float* src = sf0 + (size_t)ch * HWPIX + c0;
            for (int i = tid; i < m; i += 256) buf[ch][i] = src[i];   // coalesced
        }
        __syncthreads();
        if (tid < 5) {
            float a = acc;
            const float* bp = buf[tid];
            for (int i = 0; i < m; ++i) a = a + bp[i];   // exact ascending chain
            acc = a;
        }
        __syncthreads();
    }
    if (tid < 5 && cnt > 0) {                // where(counts>0, sums/counts, old)
        centers[(b * KSEG + k) * 5 + tid] = acc / (float)cnt;
    }
}

extern "C" void kernel_launch(void* const* d_in, const int* in_sizes, int n_in,
                              void* d_out, int out_size, void* d_ws, size_t ws_size,
                              hipStream_t stream) {
    const float* img = (const float*)d_in[0];
    float* outLab = (float*)d_out;                         // [8,224,224] labels as f32
    float* outMean = outLab + (size_t)BATCH * HWPIX;       // [8,224,224,3]

    char* ws = (char*)d_ws;
    float* centers = (float*)ws;  ws += (size_t)BATCH * KSEG * 5 * sizeof(float);
    int* labels    = (int*)ws;    ws += (size_t)BATCH * HWPIX * sizeof(int);
    int* blockHist = (int*)ws;    ws += (size_t)BATCH * KSEG * NSUB * sizeof(int);
    int* offsets   = (int*)ws;    ws += (size_t)BATCH * KSEG * NSUB * sizeof(int);
    float* sortedF = (float*)ws;  ws += (size_t)BATCH * 5 * HWPIX * sizeof(float);
    int* cbase     = (int*)ws;    ws += (size_t)BATCH * KSEG * sizeof(int);
    int* ccount    = (int*)ws;    ws += (size_t)BATCH * KSEG * sizeof(int);

    k_init<<<dim3(BATCH), 128, 0, stream>>>(img, centers);
    for (int it = 0; it < NITER; ++it) {
        k_assign<<<dim3(NTILE, BATCH), 256, 0, stream>>>(img, centers, labels, blockHist,
                                                         outLab, outMean, 0);
        k_mid<<<dim3(KSEG, BATCH), 64, 0, stream>>>(blockHist, offsets, cbase, ccount);
        k_scatter<<<dim3(NSUB, BATCH), 256, 0, stream>>>(img, labels, offsets, sortedF);
        k_update<<<dim3(KSEG, BATCH), 256, 0, stream>>>(sortedF, cbase, ccount, centers);
    }
    k_assign<<<dim3(NTILE, BATCH), 256, 0, stream>>>(img, centers, labels, blockHist,
                                                     outLab, outMean, 1);
}

// Round 9
// 586.191 us; speedup vs baseline: 3.8072x; 1.5824x over previous
//
#include <hip/hip_runtime.h>
#include <math.h>

// SLIC superpixel segmentation — bit-faithful f32 reimplementation of the JAX ref
// (XLA CPU semantics). Numerics decisions, all aimed at exact label match:
//  - dot(feats, centers) replicates Eigen sgemm: sequential k=0..4 FMA chain.
//  - f_sq / c_sq: rounded squares, sequential adds, NO fma (fp contract off).
//  - d = (f_sq + c_sq) - 2*dot, three separately-rounded ops.
//  - strict-< argmin (first occurrence, == jnp.argmin).
//  - segment_sum: EXACT ascending-pixel-index sequential adds per cluster,
//    via stable counting sort (sub-tile hist -> offsets -> rank scatter).
// R9: kill the standalone reduction kernel (R6 prefix ~30-40us, R8 mid 43us —
// every 8-block latency-bound variant loses). Offsets are now computed as a
// redundant prologue INSIDE each scatter block: 196 coalesced row loads of the
// batch hist (78KB, L2-resident) -> cnt/part/base in LDS. Paid in parallel by
// 1568 blocks (~3.6us aggregate L2 traffic) instead of serially. Block sub==0
// writes cbase/ccount for update. Assign hist write back to coalesced
// [b][sub][k]. 3 kernels/iter, 32 dispatches. Float math untouched.

#pragma clang fp contract(off)

#define BATCH 8
#define HH 224
#define WW 224
#define HWPIX (HH * WW)        // 50176
#define KSEG 100
#define NSUB 196               // 256-px sub-tiles per batch
#define NTILE 49               // 1024-px assign tiles per batch
#define NITER 10
#define UCHUNK 2048            // update LDS chunk: 5*(2048+1)*4B = 40.98KB

__device__ __forceinline__ float get_ratio() {
    double S = sqrt((double)(HH * WW) / (double)KSEG);
    return (float)(10.0 / S);
}

__global__ void k_init(const float* __restrict__ img, float* __restrict__ centers) {
#pragma clang fp contract(off)
    int b = blockIdx.x;
    int k = threadIdx.x;
    if (k >= KSEG) return;
    int i = k / 10, j = k % 10;
    int y = (int)floor(((i + 0.5) * (double)HH) / 10.0);
    int x = (int)floor(((j + 0.5) * (double)WW) / 10.0);
    float ratio = get_ratio();
    int n = y * WW + x;
    const float* p = img + ((size_t)b * HWPIX + n) * 3;
    float* c = centers + (b * KSEG + k) * 5;
    c[0] = (float)y * ratio;
    c[1] = (float)x * ratio;
    c[2] = p[0];
    c[3] = p[1];
    c[4] = p[2];
}

// 4 pixels per thread (n0 + {0,256,512,768}); hist per 256-px sub-tile,
// layout [b][sub][k] (coalesced writes). mode 0: labels+hist. mode 1: outputs.
__global__ void k_assign(const float* __restrict__ img, const float* __restrict__ centers,
                         int* __restrict__ labels, int* __restrict__ blockHist,
                         float* __restrict__ outLab, float* __restrict__ outMean, int mode) {
#pragma clang fp contract(off)
    __shared__ float c8[KSEG * 8];   // [c0,c1,c2,c3,c4,csq,pad,pad] per cluster
    __shared__ int hist[4 * KSEG];
    int b = blockIdx.y, tile = blockIdx.x, tid = threadIdx.x;

    for (int i = tid; i < KSEG * 5; i += 256) {
        int k = i / 5, f = i - 5 * k;
        c8[k * 8 + f] = centers[(size_t)b * KSEG * 5 + i];
    }
    for (int i = tid; i < 4 * KSEG; i += 256) hist[i] = 0;
    __syncthreads();
    if (tid < KSEG) {
        const float* ck = c8 + tid * 8;
        float s = ck[0] * ck[0];             // XLA fused mul+reduce: no fma, seq adds
        s = s + ck[1] * ck[1];
        s = s + ck[2] * ck[2];
        s = s + ck[3] * ck[3];
        s = s + ck[4] * ck[4];
        c8[tid * 8 + 5] = s;
    }
    __syncthreads();

    float ratio = get_ratio();
    int n0 = tile * 1024 + tid;
    float yf[4], xf[4], rr[4], gg[4], bb[4], fsq[4], dmin[4];
    int kb[4];
#pragma unroll
    for (int p = 0; p < 4; ++p) {
        int n = n0 + p * 256;
        int y = n / WW, x = n - y * WW;
        yf[p] = (float)y * ratio;
        xf[p] = (float)x * ratio;
        const float* pp = img + ((size_t)b * HWPIX + n) * 3;
        rr[p] = pp[0]; gg[p] = pp[1]; bb[p] = pp[2];
        float s = yf[p] * yf[p];             // no fma, seq adds (XLA reduce)
        s = s + xf[p] * xf[p];
        s = s + rr[p] * rr[p];
        s = s + gg[p] * gg[p];
        s = s + bb[p] * bb[p];
        fsq[p] = s;
        dmin[p] = INFINITY;
        kb[p] = 0;
    }

    for (int k = 0; k < KSEG; ++k) {
        float4 v0 = *reinterpret_cast<const float4*>(&c8[k * 8]);  // ds_read_b128
        float c4v = c8[k * 8 + 4];
        float csqv = c8[k * 8 + 5];
#pragma unroll
        for (int p = 0; p < 4; ++p) {
            // Eigen sgemm micro-kernel: sequential FMA chain over contracted dim
            float dot = yf[p] * v0.x;        // == fma(yf, c0, 0)
            dot = __fmaf_rn(xf[p], v0.y, dot);
            dot = __fmaf_rn(rr[p], v0.z, dot);
            dot = __fmaf_rn(gg[p], v0.w, dot);
            dot = __fmaf_rn(bb[p], c4v, dot);
            float d = (fsq[p] + csqv) - 2.0f * dot;   // three separately-rounded ops
            if (d < dmin[p]) { dmin[p] = d; kb[p] = k; }  // strict < == jnp.argmin
        }
    }

#pragma unroll
    for (int p = 0; p < 4; ++p)
        labels[(size_t)b * HWPIX + n0 + p * 256] = kb[p];

    if (mode == 0) {
#pragma unroll
        for (int p = 0; p < 4; ++p) atomicAdd(&hist[p * KSEG + kb[p]], 1);
        __syncthreads();
        for (int i = tid; i < 4 * KSEG; i += 256) {
            int part = i / KSEG, k = i - part * KSEG;
            blockHist[((size_t)b * NSUB + tile * 4 + part) * KSEG + k] = hist[i];
        }
    } else {
#pragma unroll
        for (int p = 0; p < 4; ++p) {
            int n = n0 + p * 256;
            outLab[(size_t)b * HWPIX + n] = (float)kb[p];
            float* om = outMean + ((size_t)b * HWPIX + n) * 3;
            om[0] = c8[kb[p] * 8 + 2];
            om[1] = c8[kb[p] * 8 + 3];
            om[2] = c8[kb[p] * 8 + 4];
        }
    }
}

// Fused offsets + stable scatter. Prologue: each block reads the batch hist
// (196 coalesced 400B rows, L2-resident) -> cnt[k] (all subs), part[k]
// (subs < mine); base[k] = exclusive scan of cnt. pos = base+part+rank.
// Block sub==0 also writes cbase/ccount for k_update.
__global__ void k_scatter(const float* __restrict__ img, const int* __restrict__ labels,
                          const int* __restrict__ blockHist, float* __restrict__ sortedF,
                          int* __restrict__ cbase, int* __restrict__ ccount) {
#pragma clang fp contract(off)
    __shared__ int cnt[KSEG];
    __shared__ int part[KSEG];
    __shared__ int base[KSEG];
    __shared__ int whist[4 * KSEG];
    int b = blockIdx.y, sub = blockIdx.x, tid = threadIdx.x;
    int lane = tid & 63, w = tid >> 6;

    if (tid < KSEG) {
        const int* hb = blockHist + (size_t)b * NSUB * KSEG + tid;
        int c = 0, p = 0;
        for (int s = 0; s < NSUB; ++s) {     // lanes 0..99 -> consecutive addrs
            int v = hb[(size_t)s * KSEG];
            c += v;
            p += (s < sub) ? v : 0;
        }
        cnt[tid] = c;
        part[tid] = p;
    }
    for (int i = tid; i < 4 * KSEG; i += 256) whist[i] = 0;
    __syncthreads();
    if (tid < KSEG) {
        int bsum = 0;
        for (int j = 0; j < tid; ++j) bsum += cnt[j];
        base[tid] = bsum;
        if (sub == 0) {
            cbase[b * KSEG + tid] = bsum;
            ccount[b * KSEG + tid] = cnt[tid];
        }
    }

    int n = sub * 256 + tid;
    int my = labels[(size_t)b * HWPIX + n];
    int rank_w = 0, cnt_w = 0;
    for (int l = 0; l < 64; ++l) {
        int ll = __shfl(my, l);
        if (ll == my) { cnt_w++; if (l < lane) rank_w++; }
    }
    __syncthreads();                         // base/part ready; whist zeroed
    if (rank_w == 0) whist[w * KSEG + my] = cnt_w;   // one writer per (wave,label)
    __syncthreads();
    int rank = rank_w;
    for (int w2 = 0; w2 < w; ++w2) rank += whist[w2 * KSEG + my];

    int pos = base[my] + part[my] + rank;
    int y = n / WW, x = n - y * WW;
    float ratio = get_ratio();
    const float* p = img + ((size_t)b * HWPIX + n) * 3;   // coalesced
    float* sf = sortedF + (size_t)b * 5 * HWPIX;
    sf[0 * HWPIX + pos] = (float)y * ratio;
    sf[1 * HWPIX + pos] = (float)x * ratio;
    sf[2 * HWPIX + pos] = p[0];
    sf[3 * HWPIX + pos] = p[1];
    sf[4 * HWPIX + pos] = p[2];
}

// One workgroup per (batch,cluster): 256 threads stage 5 x cnt sorted values
// into LDS (lane-coalesced), then 5 lanes do the EXACT ascending serial sums.
__global__ void k_update(const float* __restrict__ sortedF, const int* __restrict__ cbase,
                         const int* __restrict__ ccount, float* __restrict__ centers) {
#pragma clang fp contract(off)
    __shared__ float buf[5][UCHUNK + 1];     // +1: rows land in different banks
    int k = blockIdx.x, b = blockIdx.y, tid = threadIdx.x;
    int base = cbase[b * KSEG + k], cnt = ccount[b * KSEG + k];
    const float* sf0 = sortedF + (size_t)b * 5 * HWPIX + base;
    float acc = 0.f;
    for (int c0 = 0; c0 < cnt; c0 += UCHUNK) {
        int m = min(UCHUNK, cnt - c0);
        for (int ch = 0; ch < 5; ++ch) {
            const float* src = sf0 + (size_t)ch * HWPIX + c0;
            for (int i = tid; i < m; i += 256) buf[ch][i] = src[i];   // coalesced
        }
        __syncthreads();
        if (tid < 5) {
            float a = acc;
            const float* bp = buf[tid];
            for (int i = 0; i < m; ++i) a = a + bp[i];   // exact ascending chain
            acc = a;
        }
        __syncthreads();
    }
    if (tid < 5 && cnt > 0) {                // where(counts>0, sums/counts, old)
        centers[(b * KSEG + k) * 5 + tid] = acc / (float)cnt;
    }
}

extern "C" void kernel_launch(void* const* d_in, const int* in_sizes, int n_in,
                              void* d_out, int out_size, void* d_ws, size_t ws_size,
                              hipStream_t stream) {
    const float* img = (const float*)d_in[0];
    float* outLab = (float*)d_out;                         // [8,224,224] labels as f32
    float* outMean = outLab + (size_t)BATCH * HWPIX;       // [8,224,224,3]

    char* ws = (char*)d_ws;
    float* centers = (float*)ws;  ws += (size_t)BATCH * KSEG * 5 * sizeof(float);
    int* labels    = (int*)ws;    ws += (size_t)BATCH * HWPIX * sizeof(int);
    int* blockHist = (int*)ws;    ws += (size_t)BATCH * NSUB * KSEG * sizeof(int);
    float* sortedF = (float*)ws;  ws += (size_t)BATCH * 5 * HWPIX * sizeof(float);
    int* cbase     = (int*)ws;    ws += (size_t)BATCH * KSEG * sizeof(int);
    int* ccount    = (int*)ws;    ws += (size_t)BATCH * KSEG * sizeof(int);

    k_init<<<dim3(BATCH), 128, 0, stream>>>(img, centers);
    for (int it = 0; it < NITER; ++it) {
        k_assign<<<dim3(NTILE, BATCH), 256, 0, stream>>>(img, centers, labels, blockHist,
                                                         outLab, outMean, 0);
        k_scatter<<<dim3(NSUB, BATCH), 256, 0, stream>>>(img, labels, blockHist, sortedF,
                                                         cbase, ccount);
        k_update<<<dim3(KSEG, BATCH), 256, 0, stream>>>(sortedF, cbase, ccount, centers);
    }
    k_assign<<<dim3(NTILE, BATCH), 256, 0, stream>>>(img, centers, labels, blockHist,
                                                     outLab, outMean, 1);
}